// Round 1
// baseline (289.076 us; speedup 1.0000x reference)
//
#include <hip/hip_runtime.h>

#define MN   (256 * 256)      // 65536 rows
#define DIM  512
#define NF4  (MN * (DIM / 4)) // 8388608 float4 elements
#define EPS  1e-6f

// ---------------------------------------------------------------------------
// Kernel 1: per-row squared distance to x (with +EPS on the diff, matching
// torch PairwiseDistance semantics) and global argmin via packed u64 atomicMin.
// Key = (float_bits(dist^2) << 32) | row. dist^2 >= 0 so float bits are
// monotonic; ties break to the lowest row index (argmin first-occurrence).
// One wave per row; ROWS_PER_WAVE rows looped per wave.
// ---------------------------------------------------------------------------
__global__ __launch_bounds__(256) void som_dist(const float* __restrict__ w,
                                                const float* __restrict__ x,
                                                unsigned long long* __restrict__ best) {
    const int lane = threadIdx.x & 63;
    const int wave = threadIdx.x >> 6;
    const int ROWS = 16;
    const int row0 = (blockIdx.x * 4 + wave) * ROWS;

    // each lane owns 8 consecutive columns: [lane*8, lane*8+8)
    const float4* x4 = (const float4*)x;
    const float4 xa = x4[lane * 2 + 0];
    const float4 xb = x4[lane * 2 + 1];

    float bestd = 3.4e38f;
    int   besti = 0;

    for (int r = 0; r < ROWS; ++r) {
        const int row = row0 + r;
        const float4* w4 = (const float4*)(w + (size_t)row * DIM);
        const float4 wa = w4[lane * 2 + 0];
        const float4 wb = w4[lane * 2 + 1];

        float d, s;
        d = xa.x - wa.x + EPS; s  = d * d;
        d = xa.y - wa.y + EPS; s += d * d;
        d = xa.z - wa.z + EPS; s += d * d;
        d = xa.w - wa.w + EPS; s += d * d;
        d = xb.x - wb.x + EPS; s += d * d;
        d = xb.y - wb.y + EPS; s += d * d;
        d = xb.z - wb.z + EPS; s += d * d;
        d = xb.w - wb.w + EPS; s += d * d;

        // wave-wide butterfly sum (64 lanes)
        #pragma unroll
        for (int off = 1; off < 64; off <<= 1)
            s += __shfl_xor(s, off, 64);

        if (s < bestd) { bestd = s; besti = row; }
    }

    if (lane == 0) {
        unsigned long long key =
            ((unsigned long long)__float_as_uint(bestd) << 32) |
            (unsigned long long)(unsigned)besti;
        atomicMin(best, key);  // device-scope by default on CDNA
    }
}

// ---------------------------------------------------------------------------
// Kernel 2: new_w = w + rate * influence(row) * (x - w), one float4/thread.
// Locations are analytic: loc[r] = ((float)(r>>8), (float)(r&255)) — exact.
// decay computed in double to match float(np.exp(-it/2000)).
// Thread 0 writes (float)bmu_idx to out[MN*DIM].
// ---------------------------------------------------------------------------
__global__ __launch_bounds__(256) void som_update(const float* __restrict__ w,
                                                  const float* __restrict__ x,
                                                  float* __restrict__ out,
                                                  const unsigned long long* __restrict__ best,
                                                  const int* __restrict__ itp) {
    const int g = blockIdx.x * 256 + threadIdx.x;  // float4 index, < NF4

    const unsigned long long key = *best;
    const int bmu = (int)(key & 0xffffffffull);

    // hedge: 'it' should be int32; if the harness handed us f32 bits, detect it
    const int iv = *itp;
    const float itf = (iv >= 0 && iv <= 2000000) ? (float)iv : __int_as_float(iv);

    const double decayd = exp(-(double)itf / 2000.0);
    const float  rate   = 0.5f * (float)decayd;
    const double sigmat = 128.0 * decayd;
    const float  twoS2  = (float)(2.0 * sigmat * sigmat);

    const float bl0 = (float)(bmu >> 8);
    const float bl1 = (float)(bmu & 255);

    if (g < NF4) {
        const int row = g >> 7;   // 128 float4 per row
        const int c   = g & 127;

        const float l0 = (float)(row >> 8);
        const float l1 = (float)(row & 255);
        const float d0 = bl0 - l0 + EPS;
        const float d1 = bl1 - l1 + EPS;
        const float ld = sqrtf(d0 * d0 + d1 * d1);   // match ref: sqrt then square
        const float infl = expf(-(ld * ld) / twoS2);
        const float f = rate * infl;

        const float4 wv = ((const float4*)w)[g];
        const float4 xv = ((const float4*)x)[c];
        float4 o;
        o.x = wv.x + f * (xv.x - wv.x);
        o.y = wv.y + f * (xv.y - wv.y);
        o.z = wv.z + f * (xv.z - wv.z);
        o.w = wv.w + f * (xv.w - wv.w);
        ((float4*)out)[g] = o;
    }

    if (g == 0) {
        out[(size_t)MN * DIM] = (float)bmu;  // Output 1 (bmu_idx), read as f32
    }
}

extern "C" void kernel_launch(void* const* d_in, const int* in_sizes, int n_in,
                              void* d_out, int out_size, void* d_ws, size_t ws_size,
                              hipStream_t stream) {
    const float* x = (const float*)d_in[0];       // (512,)
    const float* w = (const float*)d_in[1];       // (65536, 512)
    // d_in[2] = locations — recomputed analytically (exact), unused
    const int*   it = (const int*)d_in[3];        // scalar

    float* out = (float*)d_out;
    unsigned long long* best = (unsigned long long*)d_ws;

    // init argmin cell to u64-max (poison 0xAA.. would actually work, but be explicit)
    hipMemsetAsync(d_ws, 0xFF, sizeof(unsigned long long), stream);

    som_dist<<<1024, 256, 0, stream>>>(w, x, best);
    som_update<<<NF4 / 256, 256, 0, stream>>>(w, x, out, best, it);
}

// Round 2
// 279.032 us; speedup vs baseline: 1.0360x; 1.0360x over previous
//
#include <hip/hip_runtime.h>

#define MN   (256 * 256)      // 65536 rows
#define DIM  512
#define NF4  (MN * (DIM / 4)) // 8388608 float4 elements
#define EPS  1e-6f

// ---------------------------------------------------------------------------
// Kernel 1: per-row squared distance to xe = x + EPS, global argmin via packed
// u64 atomicMin. One wave per row-pass; 16 rows per wave, processed in batches
// of 8 so that loads and the 8 butterfly-reduction chains overlap (ILP) instead
// of serializing per row (R1 post-mortem: serial chain => 792 GB/s, 84 us).
// Key = (float_bits(dist^2) << 32) | row; ties -> lowest row (argmin 1st-occ).
// ---------------------------------------------------------------------------
__global__ __launch_bounds__(256) void som_dist(const float* __restrict__ w,
                                                const float* __restrict__ x,
                                                unsigned long long* __restrict__ best) {
    const int lane = threadIdx.x & 63;
    const int wave = threadIdx.x >> 6;
    const int row0 = (blockIdx.x * 4 + wave) * 16;

    // each lane owns 8 consecutive columns; fold EPS into x once:
    // (x - w + EPS) == (x + EPS) - w
    const float4* x4 = (const float4*)x;
    float4 xa = x4[lane * 2 + 0];
    float4 xb = x4[lane * 2 + 1];
    xa.x += EPS; xa.y += EPS; xa.z += EPS; xa.w += EPS;
    xb.x += EPS; xb.y += EPS; xb.z += EPS; xb.w += EPS;

    float bestd = 3.4e38f;
    int   besti = 0;

    #pragma unroll
    for (int rb = 0; rb < 16; rb += 8) {
        // issue all 16 loads up front — 16 float4 in flight per wave
        float4 wa[8], wb[8];
        #pragma unroll
        for (int j = 0; j < 8; ++j) {
            const float4* w4 = (const float4*)(w + (size_t)(row0 + rb + j) * DIM);
            wa[j] = w4[lane * 2 + 0];
            wb[j] = w4[lane * 2 + 1];
        }

        float s[8];
        #pragma unroll
        for (int j = 0; j < 8; ++j) {
            float d, t;
            d = xa.x - wa[j].x; t  = d * d;
            d = xa.y - wa[j].y; t += d * d;
            d = xa.z - wa[j].z; t += d * d;
            d = xa.w - wa[j].w; t += d * d;
            d = xb.x - wb[j].x; t += d * d;
            d = xb.y - wb[j].y; t += d * d;
            d = xb.z - wb[j].z; t += d * d;
            d = xb.w - wb[j].w; t += d * d;
            s[j] = t;
        }

        // 8 independent butterfly chains, interleaved per step => pipelined
        #pragma unroll
        for (int off = 1; off < 64; off <<= 1) {
            #pragma unroll
            for (int j = 0; j < 8; ++j)
                s[j] += __shfl_xor(s[j], off, 64);
        }

        #pragma unroll
        for (int j = 0; j < 8; ++j) {
            if (s[j] < bestd) { bestd = s[j]; besti = row0 + rb + j; }
        }
    }

    if (lane == 0) {
        unsigned long long key =
            ((unsigned long long)__float_as_uint(bestd) << 32) |
            (unsigned long long)(unsigned)besti;
        atomicMin(best, key);  // device-scope by default on CDNA
    }
}

// ---------------------------------------------------------------------------
// Kernel 2: new_w = w + rate * influence(row) * (x - w).
// One wave per row: row index (blockIdx*4 + wave) is wave-uniform, so the
// influence math scalarizes; each lane handles 2 contiguous float4 (whole row
// = 64 lanes * 8 floats). Locations analytic: loc[r] = (r>>8, r&255) — exact.
// ---------------------------------------------------------------------------
__global__ __launch_bounds__(256) void som_update(const float* __restrict__ w,
                                                  const float* __restrict__ x,
                                                  float* __restrict__ out,
                                                  const unsigned long long* __restrict__ best,
                                                  const int* __restrict__ itp) {
    const int lane = threadIdx.x & 63;
    const int row  = blockIdx.x * 4 + (threadIdx.x >> 6);   // wave-uniform

    const unsigned long long key = *best;
    const int bmu = (int)(key & 0xffffffffull);

    // hedge: 'it' should be int32; if the harness handed us f32 bits, detect it
    const int iv = *itp;
    const float itf = (iv >= 0 && iv <= 2000000) ? (float)iv : __int_as_float(iv);

    const double decayd = exp(-(double)itf / 2000.0);
    const float  rate   = 0.5f * (float)decayd;
    const double sigmat = 128.0 * decayd;
    const float  twoS2  = (float)(2.0 * sigmat * sigmat);

    const float d0 = (float)(bmu >> 8)  - (float)(row >> 8)  + EPS;
    const float d1 = (float)(bmu & 255) - (float)(row & 255) + EPS;
    const float ld = sqrtf(d0 * d0 + d1 * d1);     // match ref: sqrt then square
    const float f  = rate * expf(-(ld * ld) / twoS2);

    const size_t base = (size_t)row * 128 + lane * 2;   // float4 index
    const float4 w0 = ((const float4*)w)[base + 0];
    const float4 w1 = ((const float4*)w)[base + 1];
    const float4 x0 = ((const float4*)x)[lane * 2 + 0];
    const float4 x1 = ((const float4*)x)[lane * 2 + 1];

    float4 o0, o1;
    o0.x = w0.x + f * (x0.x - w0.x);
    o0.y = w0.y + f * (x0.y - w0.y);
    o0.z = w0.z + f * (x0.z - w0.z);
    o0.w = w0.w + f * (x0.w - w0.w);
    o1.x = w1.x + f * (x1.x - w1.x);
    o1.y = w1.y + f * (x1.y - w1.y);
    o1.z = w1.z + f * (x1.z - w1.z);
    o1.w = w1.w + f * (x1.w - w1.w);
    ((float4*)out)[base + 0] = o0;
    ((float4*)out)[base + 1] = o1;

    if (row == 0 && lane == 0) {
        out[(size_t)MN * DIM] = (float)bmu;  // Output 1 (bmu_idx), read as f32
    }
}

extern "C" void kernel_launch(void* const* d_in, const int* in_sizes, int n_in,
                              void* d_out, int out_size, void* d_ws, size_t ws_size,
                              hipStream_t stream) {
    const float* x = (const float*)d_in[0];       // (512,)
    const float* w = (const float*)d_in[1];       // (65536, 512)
    // d_in[2] = locations — recomputed analytically (exact), unused
    const int*   it = (const int*)d_in[3];        // scalar

    float* out = (float*)d_out;
    unsigned long long* best = (unsigned long long*)d_ws;

    hipMemsetAsync(d_ws, 0xFF, sizeof(unsigned long long), stream);

    som_dist<<<1024, 256, 0, stream>>>(w, x, best);
    som_update<<<MN / 4, 256, 0, stream>>>(w, x, out, best, it);
}

// Round 4
// 268.730 us; speedup vs baseline: 1.0757x; 1.0383x over previous
//
#include <hip/hip_runtime.h>

#define MN   (256 * 256)      // 65536 rows
#define DIM  512
#define EPS  1e-6f

#define NSLOT      8
#define SLOT_STRIDE 16        // u64s => 128 B between slots (separate cache lines)

typedef float vfloat4 __attribute__((ext_vector_type(4)));  // native vec for nontemporal builtin

// ---------------------------------------------------------------------------
// Kernel 1: per-row squared distance to xe = x + EPS, argmin via hierarchical
// reduction. R2 post-mortem: single-address atomicMin convoy (~4096 serialized
// RMWs ~ 50 us) was the real bottleneck, not load ILP. Now: wave best -> LDS
// block best -> atomicMin into slot[blockIdx&7] (8 slots, 128 B apart) =>
// 2048 atomics / 8 lines. Key = (bits(dist^2)<<32)|row; u64 min == argmin
// with first-occurrence tie-break.
// 2048 blocks x 4 waves x 8 rows = 65536 rows.
// ---------------------------------------------------------------------------
__global__ __launch_bounds__(256) void som_dist(const float* __restrict__ w,
                                                const float* __restrict__ x,
                                                unsigned long long* __restrict__ slots) {
    const int lane = threadIdx.x & 63;
    const int wave = threadIdx.x >> 6;
    const int row0 = (blockIdx.x * 4 + wave) * 8;

    // (x - w + EPS) == (x + EPS) - w : fold EPS into x once
    const float4* x4 = (const float4*)x;
    float4 xa = x4[lane * 2 + 0];
    float4 xb = x4[lane * 2 + 1];
    xa.x += EPS; xa.y += EPS; xa.z += EPS; xa.w += EPS;
    xb.x += EPS; xb.y += EPS; xb.z += EPS; xb.w += EPS;

    const float* p = w + (size_t)row0 * DIM + lane * 8;

    // 16 float4 loads in flight
    float4 wa[8], wb[8];
    #pragma unroll
    for (int j = 0; j < 8; ++j) {
        wa[j] = ((const float4*)(p + j * DIM))[0];
        wb[j] = ((const float4*)(p + j * DIM))[1];
    }

    float s[8];
    #pragma unroll
    for (int j = 0; j < 8; ++j) {
        float d, t;
        d = xa.x - wa[j].x; t  = d * d;
        d = xa.y - wa[j].y; t += d * d;
        d = xa.z - wa[j].z; t += d * d;
        d = xa.w - wa[j].w; t += d * d;
        d = xb.x - wb[j].x; t += d * d;
        d = xb.y - wb[j].y; t += d * d;
        d = xb.z - wb[j].z; t += d * d;
        d = xb.w - wb[j].w; t += d * d;
        s[j] = t;
    }

    // 8 interleaved butterfly chains (same serial depth, 8x issue overlap)
    #pragma unroll
    for (int off = 1; off < 64; off <<= 1) {
        #pragma unroll
        for (int j = 0; j < 8; ++j)
            s[j] += __shfl_xor(s[j], off, 64);
    }

    float bestd = s[0];
    int   besti = row0;
    #pragma unroll
    for (int j = 1; j < 8; ++j) {
        if (s[j] < bestd) { bestd = s[j]; besti = row0 + j; }
    }

    __shared__ unsigned long long wkey[4];
    if (lane == 0) {
        wkey[wave] = ((unsigned long long)__float_as_uint(bestd) << 32) |
                     (unsigned long long)(unsigned)besti;
    }
    __syncthreads();
    if (threadIdx.x == 0) {
        unsigned long long m = wkey[0];
        if (wkey[1] < m) m = wkey[1];
        if (wkey[2] < m) m = wkey[2];
        if (wkey[3] < m) m = wkey[3];
        atomicMin(&slots[(blockIdx.x & (NSLOT - 1)) * SLOT_STRIDE], m);
    }
}

// ---------------------------------------------------------------------------
// Kernel 2: new_w = w + rate * influence(row) * (x - w).
// One wave per row (row is wave-uniform => influence math scalarizes).
// Each thread min-reduces the 8 slots in registers (L1-broadcast loads).
// Locations analytic: loc[r] = (r>>8, r&255) — exact integers.
// Nontemporal stores for out: streaming output, keep w resident in L3.
// ---------------------------------------------------------------------------
__global__ __launch_bounds__(256) void som_update(const float* __restrict__ w,
                                                  const float* __restrict__ x,
                                                  float* __restrict__ out,
                                                  const unsigned long long* __restrict__ slots,
                                                  const int* __restrict__ itp) {
    const int lane = threadIdx.x & 63;
    const int row  = blockIdx.x * 4 + (threadIdx.x >> 6);   // wave-uniform

    unsigned long long m = slots[0];
    #pragma unroll
    for (int i = 1; i < NSLOT; ++i) {
        unsigned long long v = slots[i * SLOT_STRIDE];
        if (v < m) m = v;
    }
    const int bmu = (int)(m & 0xffffffffull);

    // hedge: 'it' should be int32; if the harness handed us f32 bits, detect it
    const int iv = *itp;
    const float itf = (iv >= 0 && iv <= 2000000) ? (float)iv : __int_as_float(iv);

    const double decayd = exp(-(double)itf / 2000.0);
    const float  rate   = 0.5f * (float)decayd;
    const double sigmat = 128.0 * decayd;
    const float  twoS2  = (float)(2.0 * sigmat * sigmat);

    const float d0 = (float)(bmu >> 8)  - (float)(row >> 8)  + EPS;
    const float d1 = (float)(bmu & 255) - (float)(row & 255) + EPS;
    const float ld = sqrtf(d0 * d0 + d1 * d1);     // match ref: sqrt then square
    const float f  = rate * expf(-(ld * ld) / twoS2);

    const size_t base = (size_t)row * 128 + lane * 2;   // float4 index
    const float4 w0 = ((const float4*)w)[base + 0];
    const float4 w1 = ((const float4*)w)[base + 1];
    const float4 x0 = ((const float4*)x)[lane * 2 + 0];
    const float4 x1 = ((const float4*)x)[lane * 2 + 1];

    vfloat4 o0, o1;
    o0.x = w0.x + f * (x0.x - w0.x);
    o0.y = w0.y + f * (x0.y - w0.y);
    o0.z = w0.z + f * (x0.z - w0.z);
    o0.w = w0.w + f * (x0.w - w0.w);
    o1.x = w1.x + f * (x1.x - w1.x);
    o1.y = w1.y + f * (x1.y - w1.y);
    o1.z = w1.z + f * (x1.z - w1.z);
    o1.w = w1.w + f * (x1.w - w1.w);
    __builtin_nontemporal_store(o0, (vfloat4*)out + base + 0);
    __builtin_nontemporal_store(o1, (vfloat4*)out + base + 1);

    if (row == 0 && lane == 0) {
        out[(size_t)MN * DIM] = (float)bmu;  // Output 1 (bmu_idx), read as f32
    }
}

extern "C" void kernel_launch(void* const* d_in, const int* in_sizes, int n_in,
                              void* d_out, int out_size, void* d_ws, size_t ws_size,
                              hipStream_t stream) {
    const float* x = (const float*)d_in[0];       // (512,)
    const float* w = (const float*)d_in[1];       // (65536, 512)
    // d_in[2] = locations — recomputed analytically (exact), unused
    const int*   it = (const int*)d_in[3];        // scalar

    float* out = (float*)d_out;
    unsigned long long* slots = (unsigned long long*)d_ws;

    // init all 8 argmin slots (128 B apart) to u64-max
    (void)hipMemsetAsync(d_ws, 0xFF, NSLOT * SLOT_STRIDE * sizeof(unsigned long long), stream);

    som_dist<<<2048, 256, 0, stream>>>(w, x, slots);
    som_update<<<MN / 4, 256, 0, stream>>>(w, x, out, slots, it);
}